// Round 1
// baseline (2046.824 us; speedup 1.0000x reference)
//
#include <hip/hip_runtime.h>

// SwinTransformerBlock on MI355X (gfx950).
// Pipeline:
//   k_cast x3      : fp32 -> bf16 for x, qkv_w, proj_w
//   k_mbi          : per-window packed table u16 = rpe_idx | (mask!=0)<<8
//   k_attn         : per (window,head) block: QKV GEMM (MFMA, 64x96xK=384)
//                    -> q/k/v fp32 in LDS -> bq0+bk0 -> S=q.k^T + bias + mask
//                    -> softmax -> write attn (output 2) + PV -> o1 (bf16)
//   k_rv           : r_v[b,i,h,d] = sum_j attn[b,h,i,j]*v_rpe[h,idx[i,j],d],
//                    batched over b per (h,i); RMW-adds into o1
//   k_proj         : out = (o1) @ proj_w^T + proj_b (MFMA 128x128 tiles)

typedef unsigned int u32;
typedef unsigned short u16;
typedef __attribute__((ext_vector_type(8))) short bf16x8;   // 8 bf16 in 4 VGPRs
typedef __attribute__((ext_vector_type(4))) float f32x4;

#define SCALE 0.17677669529663687f   // 32^-0.5

__device__ __forceinline__ u16 f2b(float f) {
  union { float f; u32 u; } c; c.f = f;
  u32 u = c.u;
  return (u16)((u + 0x7FFFu + ((u >> 16) & 1u)) >> 16);   // RNE
}
__device__ __forceinline__ float b2f(u16 s) {
  union { float f; u32 u; } c; c.u = ((u32)s) << 16;
  return c.f;
}
__device__ __forceinline__ void async16(void* lds, const void* g) {
  __builtin_amdgcn_global_load_lds(
      (const __attribute__((address_space(1))) u32*)g,
      (__attribute__((address_space(3))) u32*)lds, 16, 0, 0);
}

__global__ __launch_bounds__(256) void k_cast(const float* __restrict__ s,
                                              u16* __restrict__ d, int n4) {
  int i = blockIdx.x * 256 + threadIdx.x;
  int str = gridDim.x * 256;
  for (; i < n4; i += str) {
    float4 v = ((const float4*)s)[i];
    ushort4 o;
    o.x = f2b(v.x); o.y = f2b(v.y); o.z = f2b(v.z); o.w = f2b(v.w);
    ((ushort4*)d)[i] = o;
  }
}

__global__ __launch_bounds__(256) void k_mbi(const float* __restrict__ mask,
                                             const int* __restrict__ idx,
                                             u16* __restrict__ mbi) {
  int i = blockIdx.x * 256 + threadIdx.x;
  if (i >= 64 * 2401) return;
  int p = i % 2401;
  mbi[i] = (u16)(idx[p] | ((mask[i] != 0.0f) ? 256 : 0));
}

// One block per (window b, head h). 256 threads = 4 waves (2x2 wave grid).
__global__ __launch_bounds__(256) void k_attn(
    const u16* __restrict__ xb, const u16* __restrict__ wqkv,
    const float* __restrict__ qkv_b,
    const float* __restrict__ q_rpe, const float* __restrict__ k_rpe,
    const u16* __restrict__ mbi,
    float* __restrict__ attn, u16* __restrict__ o1) {
  int bh = blockIdx.x;
  int b = bh / 12, h = bh % 12;
  int tid = threadIdx.x;
  int w = tid >> 6, l = tid & 63;
  int wm = w >> 1, wn = w & 1;
  int lr = l & 15, lg = l >> 4, lk8 = lg << 3;

  __shared__ float qf[49 * 33];            // q (scaled), stride 33: conflict-free per-lane row reads
  __shared__ float kf[49 * 32];            // k rows, read via uniform broadcast
  __shared__ float vf[49 * 32];            // v rows, read via uniform broadcast
  __shared__ __align__(16) char uD[10280]; // union: {x_tile 4KB | w_tile 6KB} then {S 9604B + bqk 676B}
  __shared__ float rinvL[49];
  u16* xt = (u16*)uD;                      // [64][32] bf16
  u16* wt = (u16*)(uD + 4096);             // [96][32] bf16
  float* Sm = (float*)uD;                  // [49*49]
  float* bqkL = (float*)(uD + 9604);       // [169]

  f32x4 acc[2][3] = {};

  // ---- Phase 1: QKV GEMM, C[64x96] = X[64x384] * Wqkv_head^T ----
  int rowA = tid >> 2, c8 = (tid & 3) << 3;
  const u16* gx = xb + (size_t)(b * 49 + rowA) * 384 + c8;   // rows>=49 spill into next window: masked later
  int grB = (rowA >> 5) * 384 + h * 32 + (rowA & 31);        // qkv_w row for out-col rowA (q|k thirds)
  const u16* gw = wqkv + (size_t)grB * 384 + c8;
  const u16* gw2 = nullptr;
  if (tid < 128) {
    int c = 256 + tid, row2 = c >> 2, c82 = (c & 3) << 3;    // out-cols 64..95 (v third)
    int gr2 = (row2 >> 5) * 384 + h * 32 + (row2 & 31);
    gw2 = wqkv + (size_t)gr2 * 384 + c82;
  }

  for (int ks = 0; ks < 12; ++ks) {
    int k0 = ks * 32;
    async16(xt + tid * 8, gx + k0);
    async16(wt + tid * 8, gw + k0);
    if (tid < 128) async16(wt + (256 + tid) * 8, gw2 + k0);
    __syncthreads();
    bf16x8 af[2], bfr[3];
#pragma unroll
    for (int mi = 0; mi < 2; ++mi)
      af[mi] = *(const bf16x8*)&xt[(wm * 32 + mi * 16 + lr) * 32 + lk8];
#pragma unroll
    for (int ni = 0; ni < 3; ++ni)
      bfr[ni] = *(const bf16x8*)&wt[(wn * 48 + ni * 16 + lr) * 32 + lk8];
#pragma unroll
    for (int mi = 0; mi < 2; ++mi)
#pragma unroll
      for (int ni = 0; ni < 3; ++ni)
        acc[mi][ni] = __builtin_amdgcn_mfma_f32_16x16x32_bf16(af[mi], bfr[ni], acc[mi][ni], 0, 0, 0);
    __syncthreads();
  }

  // Epilogue: +bias, scatter into fp32 LDS q/k/v. C/D layout: col=lane&15, row=(lane>>4)*4+r.
#pragma unroll
  for (int mi = 0; mi < 2; ++mi)
#pragma unroll
    for (int ni = 0; ni < 3; ++ni)
#pragma unroll
      for (int r = 0; r < 4; ++r) {
        int row = wm * 32 + mi * 16 + lg * 4 + r;
        if (row < 49) {
          int col = wn * 48 + ni * 16 + lr;
          int g = col >> 5, cd = col & 31;
          float v = acc[mi][ni][r] + qkv_b[g * 384 + h * 32 + cd];
          if (g == 0) qf[row * 33 + cd] = v * SCALE;
          else if (g == 1) kf[row * 32 + cd] = v;
          else vf[row * 32 + cd] = v;
        }
      }
  __syncthreads();

  // ---- Pass A: S[i][j] = q_i . k_j (q per-lane in regs, k broadcast) ----
  float qreg[32];
  {
    if (l < 49) {
#pragma unroll
      for (int d2 = 0; d2 < 32; ++d2) qreg[d2] = qf[l * 33 + d2];
    }
    int j0 = w * 13, j1 = (w == 3) ? 49 : (j0 + 13);
    for (int j = j0; j < j1; ++j) {
      const float4* kr = (const float4*)&kf[j * 32];
      float s = 0.f;
#pragma unroll
      for (int q4 = 0; q4 < 8; ++q4) {
        float4 kv = kr[q4];
        s += qreg[q4 * 4 + 0] * kv.x + qreg[q4 * 4 + 1] * kv.y +
             qreg[q4 * 4 + 2] * kv.z + qreg[q4 * 4 + 3] * kv.w;
      }
      if (l < 49) Sm[l * 49 + j] = s;
    }
  }
  // bq0 + bk0 over the 169-entry table (token 0 of q/k; q already scaled)
  if (tid < 169) {
    float s = 0.f;
#pragma unroll 8
    for (int d2 = 0; d2 < 32; ++d2)
      s += qf[d2] * q_rpe[(h * 32 + d2) * 169 + tid] +
           kf[d2] * k_rpe[(h * 32 + d2) * 169 + tid];
    bqkL[tid] = s;
  }
  __syncthreads();

  // ---- Pass B: += contextual bias (gather) + shift mask ----
  const u16* mrow = mbi + (size_t)(b & 63) * 2401;
  for (int p = tid; p < 2401; p += 256) {
    u16 t = mrow[p];
    Sm[p] += bqkL[t & 255] - 100.f * (float)(t >> 8);
  }
  __syncthreads();

  // ---- Softmax (row-serial, lanes 0..48 of wave 0) ----
  if (tid < 49) {
    float m = -1e30f;
    for (int j = 0; j < 49; ++j) m = fmaxf(m, Sm[tid * 49 + j]);
    float sum = 0.f;
    for (int j = 0; j < 49; ++j) {
      float e = __expf(Sm[tid * 49 + j] - m);
      Sm[tid * 49 + j] = e;
      sum += e;
    }
    rinvL[tid] = 1.f / sum;
  }
  __syncthreads();

  // ---- Pass C: write attn, then PV -> o1 ----
  float* ao = attn + (size_t)bh * 2401;
  for (int p = tid; p < 2401; p += 256) ao[p] = Sm[p] * rinvL[p / 49];
  {
    int d0 = w * 8;   // wave covers 8 of 32 head dims; lanes = token i
    float o[8] = {0, 0, 0, 0, 0, 0, 0, 0};
    for (int j = 0; j < 49; ++j) {
      float pj = (l < 49) ? Sm[l * 49 + j] : 0.f;
      const float4* vr = (const float4*)&vf[j * 32 + d0];
      float4 v0 = vr[0], v1 = vr[1];
      o[0] += pj * v0.x; o[1] += pj * v0.y; o[2] += pj * v0.z; o[3] += pj * v0.w;
      o[4] += pj * v1.x; o[5] += pj * v1.y; o[6] += pj * v1.z; o[7] += pj * v1.w;
    }
    if (l < 49) {
      float ri = rinvL[l];
      u16 u[8];
#pragma unroll
      for (int e = 0; e < 8; ++e) u[e] = f2b(o[e] * ri);
      uint4 pk;
      pk.x = (u32)u[0] | ((u32)u[1] << 16);
      pk.y = (u32)u[2] | ((u32)u[3] << 16);
      pk.z = (u32)u[4] | ((u32)u[5] << 16);
      pk.w = (u32)u[6] | ((u32)u[7] << 16);
      *(uint4*)&o1[((size_t)(b * 49 + l)) * 384 + h * 32 + d0] = pk;
    }
  }
}

// r_v: per (h, i, batch-chunk of 64): R[b,d] = sum_j attn[b,h,i,j] * v_rpe[h, idx[i,j], d]
// RMW-adds into o1 (exclusive element ownership per block; kernels stream-ordered).
__global__ __launch_bounds__(256) void k_rv(
    const float* __restrict__ attn, const int* __restrict__ idx,
    const float* __restrict__ v_rpe, u16* __restrict__ o1) {
  int bx = blockIdx.x;
  int bc = bx & 31;
  int hi = bx >> 5;
  int i = hi % 49, h = hi / 49;
  int b0 = bc * 64;
  int tid = threadIdx.x;
  __shared__ float wf[49 * 32];
  __shared__ float aL[64 * 49];
  for (int e = tid; e < 1568; e += 256) {
    int j = e >> 5, d = e & 31;
    wf[e] = v_rpe[((size_t)h * 169 + idx[i * 49 + j]) * 32 + d];
  }
  for (int e = tid; e < 3136; e += 256) {
    int bl = e / 49, j = e - bl * 49;
    aL[e] = attn[((size_t)(b0 + bl) * 12 + h) * 2401 + i * 49 + j];
  }
  __syncthreads();
  int d = tid & 31, bg = tid >> 5;
  for (int bl = bg; bl < 64; bl += 8) {
    float r = 0.f;
#pragma unroll 7
    for (int j = 0; j < 49; ++j) r += aL[bl * 49 + j] * wf[j * 32 + d];
    size_t oo = ((size_t)(b0 + bl) * 49 + i) * 384 + h * 32 + d;
    o1[oo] = f2b(b2f(o1[oo]) + r);
  }
}

// out[100352x384] = o1[100352x384](bf16) @ proj_w^T + proj_b, fp32 out.
__global__ __launch_bounds__(256) void k_proj(
    const u16* __restrict__ A, const u16* __restrict__ Bw,
    const float* __restrict__ bias, float* __restrict__ out) {
  int bx = blockIdx.x;
  int mt = bx / 3, nt = bx - mt * 3;
  size_t m0 = (size_t)mt * 128;
  int n0 = nt * 128;
  int tid = threadIdx.x;
  int w = tid >> 6, l = tid & 63;
  int wm = w >> 1, wn = w & 1;
  int lr = l & 15, lg = l >> 4, lk8 = lg << 3;
  __shared__ u16 At[128 * 32];
  __shared__ u16 Bt[128 * 32];
  f32x4 acc[4][4] = {};
  int row = tid >> 2, c8 = (tid & 3) << 3;
  const u16* gA = A + (m0 + row) * 384 + c8;
  const u16* gA2 = A + (m0 + row + 64) * 384 + c8;
  const u16* gB = Bw + (size_t)(n0 + row) * 384 + c8;
  const u16* gB2 = Bw + (size_t)(n0 + row + 64) * 384 + c8;
  for (int ks = 0; ks < 12; ++ks) {
    int k0 = ks * 32;
    async16(At + tid * 8, gA + k0);
    async16(At + (256 + tid) * 8, gA2 + k0);
    async16(Bt + tid * 8, gB + k0);
    async16(Bt + (256 + tid) * 8, gB2 + k0);
    __syncthreads();
    bf16x8 af[4], bfr[4];
#pragma unroll
    for (int mi = 0; mi < 4; ++mi)
      af[mi] = *(const bf16x8*)&At[(wm * 64 + mi * 16 + lr) * 32 + lk8];
#pragma unroll
    for (int ni = 0; ni < 4; ++ni)
      bfr[ni] = *(const bf16x8*)&Bt[(wn * 64 + ni * 16 + lr) * 32 + lk8];
#pragma unroll
    for (int mi = 0; mi < 4; ++mi)
#pragma unroll
      for (int ni = 0; ni < 4; ++ni)
        acc[mi][ni] = __builtin_amdgcn_mfma_f32_16x16x32_bf16(af[mi], bfr[ni], acc[mi][ni], 0, 0, 0);
    __syncthreads();
  }
#pragma unroll
  for (int mi = 0; mi < 4; ++mi)
#pragma unroll
    for (int ni = 0; ni < 4; ++ni)
#pragma unroll
      for (int r = 0; r < 4; ++r) {
        int rr = wm * 64 + mi * 16 + lg * 4 + r;
        int cc = wn * 64 + ni * 16 + lr;
        out[(m0 + rr) * 384 + (size_t)(n0 + cc)] = acc[mi][ni][r] + bias[n0 + cc];
      }
}

extern "C" void kernel_launch(void* const* d_in, const int* in_sizes, int n_in,
                              void* d_out, int out_size, void* d_ws, size_t ws_size,
                              hipStream_t stream) {
  const float* x      = (const float*)d_in[0];
  const float* mask   = (const float*)d_in[1];
  const int*   rpe    = (const int*)d_in[2];
  const float* qkv_w  = (const float*)d_in[3];
  const float* qkv_b  = (const float*)d_in[4];
  const float* proj_w = (const float*)d_in[5];
  const float* proj_b = (const float*)d_in[6];
  const float* q_rpe  = (const float*)d_in[7];
  const float* k_rpe  = (const float*)d_in[8];
  const float* v_rpe  = (const float*)d_in[9];

  float* out  = (float*)d_out;
  float* attn = out + (size_t)100352 * 384;   // output 2 starts after output 1

  char* ws = (char*)d_ws;
  u16* xb     = (u16*)ws;                       // x bf16:     77,070,336 B
  u16* wqkvb  = (u16*)(ws + 77070336);          // qkv_w bf16:    884,736 B
  u16* wprojb = (u16*)(ws + 77955072);          // proj_w bf16:   294,912 B
  u16* mbi    = (u16*)(ws + 78249984);          // mask+idx:      307,328 B
  u16* o1     = (u16*)(ws + 78557312);          // attn@v (+r_v): 77,070,336 B  (end ~155.6 MB)

  k_cast<<<2048, 256, 0, stream>>>(x, xb, 9633792);
  k_cast<<<432, 256, 0, stream>>>(qkv_w, wqkvb, 110592);
  k_cast<<<144, 256, 0, stream>>>(proj_w, wprojb, 36864);
  k_mbi<<<601, 256, 0, stream>>>(mask, rpe, mbi);
  k_attn<<<24576, 256, 0, stream>>>(xb, wqkvb, qkv_b, q_rpe, k_rpe, mbi, attn, o1);
  k_rv<<<18816, 256, 0, stream>>>(attn, rpe, v_rpe, o1);
  k_proj<<<2352, 256, 0, stream>>>(o1, wprojb, proj_b, out);
}

// Round 2
// 771.571 us; speedup vs baseline: 2.6528x; 2.6528x over previous
//
#include <hip/hip_runtime.h>

// SwinTransformerBlock on MI355X (gfx950).
// Pipeline:
//   k_cast x3 : fp32 -> bf16 for x, qkv_w, proj_w
//   k_mbi     : per-window packed table u16 = rpe_idx | (mask!=0)<<8
//   k_qkv     : big MFMA GEMM qkv = x @ qkv_w^T + b (q pre-scaled), bf16 out
//   k_attn    : one WAVE per (b,h): S^T = mfma(K,Q) -> bias/mask gather ->
//               wave-parallel softmax -> attn write (fp32 from regs) ->
//               P(bf16,swizzled LDS) -> O^T = mfma(V^T,P) -> o1 (bf16)
//   k_rv      : r_v RMW-add into o1
//   k_proj    : out = o1 @ proj_w^T + proj_b (MFMA 128x128 tiles)

typedef unsigned int u32;
typedef unsigned short u16;
typedef __attribute__((ext_vector_type(8))) short bf16x8;
typedef __attribute__((ext_vector_type(4))) float f32x4;

#define SCALE 0.17677669529663687f   // 32^-0.5

__device__ __forceinline__ u16 f2b(float f) {
  union { float f; u32 u; } c; c.f = f;
  u32 u = c.u;
  return (u16)((u + 0x7FFFu + ((u >> 16) & 1u)) >> 16);   // RNE
}
__device__ __forceinline__ float b2f(u16 s) {
  union { float f; u32 u; } c; c.u = ((u32)s) << 16;
  return c.f;
}
__device__ __forceinline__ void async16(void* lds, const void* g) {
  __builtin_amdgcn_global_load_lds(
      (const __attribute__((address_space(1))) u32*)g,
      (__attribute__((address_space(3))) u32*)lds, 16, 0, 0);
}

__global__ __launch_bounds__(256) void k_cast(const float* __restrict__ s,
                                              u16* __restrict__ d, int n4) {
  int i = blockIdx.x * 256 + threadIdx.x;
  int str = gridDim.x * 256;
  for (; i < n4; i += str) {
    float4 v = ((const float4*)s)[i];
    ushort4 o;
    o.x = f2b(v.x); o.y = f2b(v.y); o.z = f2b(v.z); o.w = f2b(v.w);
    ((ushort4*)d)[i] = o;
  }
}

__global__ __launch_bounds__(256) void k_mbi(const float* __restrict__ mask,
                                             const int* __restrict__ idx,
                                             u16* __restrict__ mbi) {
  int i = blockIdx.x * 256 + threadIdx.x;
  if (i >= 64 * 2401) return;
  int p = i % 2401;
  mbi[i] = (u16)(idx[p] | ((mask[i] != 0.0f) ? 256 : 0));
}

// qkv[100352][1152](bf16) = x[100352][384](bf16) @ qkv_w^T + qkv_b; q cols scaled.
__global__ __launch_bounds__(256) void k_qkv(
    const u16* __restrict__ A, const u16* __restrict__ Bw,
    const float* __restrict__ bias, u16* __restrict__ outq) {
  int bx = blockIdx.x;
  int mt = bx / 9, nt = bx - mt * 9;
  size_t m0 = (size_t)mt * 128;
  int n0 = nt * 128;
  int tid = threadIdx.x;
  int w = tid >> 6, l = tid & 63;
  int wm = w >> 1, wn = w & 1;
  int lr = l & 15, lg = l >> 4, lk8 = lg << 3;
  __shared__ u16 At[128 * 32];
  __shared__ u16 Bt[128 * 32];
  f32x4 acc[4][4] = {};
  int row = tid >> 2, c8 = (tid & 3) << 3;
  const u16* gA = A + (m0 + row) * 384 + c8;
  const u16* gA2 = A + (m0 + row + 64) * 384 + c8;
  const u16* gB = Bw + (size_t)(n0 + row) * 384 + c8;
  const u16* gB2 = Bw + (size_t)(n0 + row + 64) * 384 + c8;
  for (int ks = 0; ks < 12; ++ks) {
    int k0 = ks * 32;
    async16(At + tid * 8, gA + k0);
    async16(At + (256 + tid) * 8, gA2 + k0);
    async16(Bt + tid * 8, gB + k0);
    async16(Bt + (256 + tid) * 8, gB2 + k0);
    __syncthreads();
    bf16x8 af[4], bfr[4];
#pragma unroll
    for (int mi = 0; mi < 4; ++mi)
      af[mi] = *(const bf16x8*)&At[(wm * 64 + mi * 16 + lr) * 32 + lk8];
#pragma unroll
    for (int ni = 0; ni < 4; ++ni)
      bfr[ni] = *(const bf16x8*)&Bt[(wn * 64 + ni * 16 + lr) * 32 + lk8];
#pragma unroll
    for (int mi = 0; mi < 4; ++mi)
#pragma unroll
      for (int ni = 0; ni < 4; ++ni)
        acc[mi][ni] = __builtin_amdgcn_mfma_f32_16x16x32_bf16(af[mi], bfr[ni], acc[mi][ni], 0, 0, 0);
    __syncthreads();
  }
#pragma unroll
  for (int ni = 0; ni < 4; ++ni) {
    int cc = n0 + wn * 64 + ni * 16 + lr;
    float bv = bias[cc];
    float sc = (cc < 384) ? SCALE : 1.0f;
#pragma unroll
    for (int mi = 0; mi < 4; ++mi)
#pragma unroll
      for (int r = 0; r < 4; ++r) {
        size_t rr = m0 + wm * 64 + mi * 16 + lg * 4 + r;
        outq[rr * 1152 + cc] = f2b((acc[mi][ni][r] + bv) * sc);
      }
  }
}

// One WAVE per (b,h); block = 4 waves = heads hg*4..hg*4+3 of one window b.
__global__ __launch_bounds__(256) void k_attn(
    const u16* __restrict__ qkv,
    const float* __restrict__ q_rpe, const float* __restrict__ k_rpe,
    const u16* __restrict__ mbi,
    float* __restrict__ attn, u16* __restrict__ o1) {
  int blk = blockIdx.x;
  int b = blk / 3, hg = blk % 3;
  int tid = threadIdx.x, w = tid >> 6, l = tid & 63;
  int h = hg * 4 + w;
  int lr = l & 15, g = l >> 4;

  __shared__ u16 mbiL[2408];
  __shared__ __align__(16) u16 vL[4][2048];   // [wave][j(64)][d(32)]
  __shared__ __align__(16) u16 pL[4][4096];   // [wave][qi(64)][kj(64)] swizzled
  __shared__ float bqkL[4][172];

  const u16* qbase = qkv + (size_t)b * 49 * 1152 + h * 32;
  const u16* kbase = qbase + 384;
  const u16* vbase = qbase + 768;

  // cooperative mask+index table load
  {
    const u16* mrow = mbi + (size_t)(b & 63) * 2401;
    for (int p = tid; p < 2401; p += 256) mbiL[p] = mrow[p];
  }
  // V rows -> LDS (lane-contiguous dest for global_load_lds)
  u16* vw = &vL[w][0];
#pragma unroll
  for (int p = 0; p < 4; ++p) {
    int j = p * 16 + (l >> 2);
    int jr = (j < 49) ? j : 48;
    async16(vw + p * 512 + l * 8, vbase + (size_t)jr * 1152 + (l & 3) * 8);
  }

  // Q/K fragments (row-major global, 16B per lane)
  bf16x8 qf[4], kf[4];
#pragma unroll
  for (int t = 0; t < 4; ++t) {
    int qi = t * 16 + lr;
    int qir = (qi < 49) ? qi : 48;
    qf[t] = *(const bf16x8*)(qbase + (size_t)qir * 1152 + g * 8);
    kf[t] = *(const bf16x8*)(kbase + (size_t)qir * 1152 + g * 8);
  }

  // S^T[kj][qi] = sum_d K[kj][d] * Q[qi][d]
  f32x4 S[4][4] = {};   // [mt(kj)][nt(qi)]
#pragma unroll
  for (int mt = 0; mt < 4; ++mt)
#pragma unroll
    for (int nt = 0; nt < 4; ++nt)
      S[mt][nt] = __builtin_amdgcn_mfma_f32_16x16x32_bf16(kf[mt], qf[nt], S[mt][nt], 0, 0, 0);

  // contextual bias table bqk[t] = q0 . q_rpe[h,:,t] + k0 . k_rpe[h,:,t]
  {
    float q0d[32], k0d[32];
#pragma unroll
    for (int d = 0; d < 32; ++d) { q0d[d] = b2f(qbase[d]); k0d[d] = b2f(kbase[d]); }
#pragma unroll
    for (int t0 = 0; t0 < 192; t0 += 64) {
      int t = t0 + l;
      if (t < 169) {
        float s = 0.f;
#pragma unroll
        for (int d = 0; d < 32; ++d)
          s += q0d[d] * q_rpe[(h * 32 + d) * 169 + t] +
               k0d[d] * k_rpe[(h * 32 + d) * 169 + t];
        bqkL[w][t] = s;
      }
    }
  }
  __syncthreads();   // mbiL + vL ready (drains vmcnt), bqkL own-wave

  // bias + mask (and padding -> -1e9)
#pragma unroll
  for (int nt = 0; nt < 4; ++nt) {
    int qi = nt * 16 + lr;
#pragma unroll
    for (int mt = 0; mt < 4; ++mt)
#pragma unroll
      for (int r = 0; r < 4; ++r) {
        int kj = mt * 16 + g * 4 + r;
        float s = S[mt][nt][r];
        if (qi < 49 && kj < 49) {
          u16 t = mbiL[qi * 49 + kj];
          s += bqkL[w][t & 255] - 100.f * (float)(t >> 8);
        } else {
          s = -1e9f;
        }
        S[mt][nt][r] = s;
      }
  }

  // wave-parallel softmax over kj (rows of S^T): per-lane reduce + xor16/32
  float rinv[4];
#pragma unroll
  for (int nt = 0; nt < 4; ++nt) {
    float m = -1e30f;
#pragma unroll
    for (int mt = 0; mt < 4; ++mt)
#pragma unroll
      for (int r = 0; r < 4; ++r) m = fmaxf(m, S[mt][nt][r]);
    m = fmaxf(m, __shfl_xor(m, 16, 64));
    m = fmaxf(m, __shfl_xor(m, 32, 64));
    float sum = 0.f;
#pragma unroll
    for (int mt = 0; mt < 4; ++mt)
#pragma unroll
      for (int r = 0; r < 4; ++r) {
        float e = __expf(S[mt][nt][r] - m);
        S[mt][nt][r] = e;
        sum += e;
      }
    sum += __shfl_xor(sum, 16, 64);
    sum += __shfl_xor(sum, 32, 64);
    rinv[nt] = 1.f / sum;
  }

  // attn output (fp32, exact from regs; L2 merges the scattered stores)
  {
    float* ao = attn + (size_t)(b * 12 + h) * 2401;
#pragma unroll
    for (int nt = 0; nt < 4; ++nt) {
      int qi = nt * 16 + lr;
      if (qi < 49) {
        float riv = rinv[nt];
#pragma unroll
        for (int mt = 0; mt < 3; ++mt)
#pragma unroll
          for (int r = 0; r < 4; ++r)
            ao[qi * 49 + mt * 16 + g * 4 + r] = S[mt][nt][r] * riv;
        if (g == 0) ao[qi * 49 + 48] = S[3][nt][0] * riv;
      }
    }
  }

  // P (unnormalized exp) -> LDS bf16, XOR-swizzled rows
  u16* pw = &pL[w][0];
#pragma unroll
  for (int nt = 0; nt < 4; ++nt) {
    int qi = nt * 16 + lr;
    int swz = (qi & 7) << 4;
#pragma unroll
    for (int mt = 0; mt < 4; ++mt) {
      u32 w0 = (u32)f2b(S[mt][nt][0]) | ((u32)f2b(S[mt][nt][1]) << 16);
      u32 w1 = (u32)f2b(S[mt][nt][2]) | ((u32)f2b(S[mt][nt][3]) << 16);
      int off = (qi * 128 + mt * 32 + g * 8) ^ swz;
      uint2 pk = {w0, w1};
      *(uint2*)((char*)pw + off) = pk;
    }
  }

  // O^T[d][i] = sum_j V^T[d][j] * P[i][j]
  f32x4 O[2][4] = {};   // [mtd(d)][nti(i)]
#pragma unroll
  for (int ks = 0; ks < 2; ++ks) {
    bf16x8 pb[4];
#pragma unroll
    for (int nti = 0; nti < 4; ++nti) {
      int qi = nti * 16 + lr;
      int off = (qi * 128 + ks * 64 + g * 16) ^ ((qi & 7) << 4);
      pb[nti] = *(const bf16x8*)((const char*)pw + off);
    }
    bf16x8 va[2];
#pragma unroll
    for (int mtd = 0; mtd < 2; ++mtd)
#pragma unroll
      for (int jj = 0; jj < 8; ++jj)
        va[mtd][jj] = (short)vw[(ks * 32 + g * 8 + jj) * 32 + mtd * 16 + lr];
#pragma unroll
    for (int mtd = 0; mtd < 2; ++mtd)
#pragma unroll
      for (int nti = 0; nti < 4; ++nti)
        O[mtd][nti] = __builtin_amdgcn_mfma_f32_16x16x32_bf16(va[mtd], pb[nti], O[mtd][nti], 0, 0, 0);
  }

  // store o1 (bf16, 4 consecutive d packed per store)
  {
    u16* ob = o1 + (size_t)b * 49 * 384 + h * 32;
#pragma unroll
    for (int nti = 0; nti < 4; ++nti) {
      int i = nti * 16 + lr;
      if (i < 49) {
        float riv = rinv[nti];
#pragma unroll
        for (int mtd = 0; mtd < 2; ++mtd) {
          u32 w0 = (u32)f2b(O[mtd][nti][0] * riv) | ((u32)f2b(O[mtd][nti][1] * riv) << 16);
          u32 w1 = (u32)f2b(O[mtd][nti][2] * riv) | ((u32)f2b(O[mtd][nti][3] * riv) << 16);
          uint2 pk = {w0, w1};
          *(uint2*)&ob[(size_t)i * 384 + mtd * 16 + g * 4] = pk;
        }
      }
    }
  }
}

// r_v: per (h, i, batch-chunk of 64): R[b,d] = sum_j attn[b,h,i,j] * v_rpe[h, idx[i,j], d]
__global__ __launch_bounds__(256) void k_rv(
    const float* __restrict__ attn, const int* __restrict__ idx,
    const float* __restrict__ v_rpe, u16* __restrict__ o1) {
  int bx = blockIdx.x;
  int bc = bx & 31;
  int hi = bx >> 5;
  int i = hi % 49, h = hi / 49;
  int b0 = bc * 64;
  int tid = threadIdx.x;
  __shared__ float wf[49 * 32];
  __shared__ float aL[64 * 49];
  for (int e = tid; e < 1568; e += 256) {
    int j = e >> 5, d = e & 31;
    wf[e] = v_rpe[((size_t)h * 169 + idx[i * 49 + j]) * 32 + d];
  }
  for (int e = tid; e < 3136; e += 256) {
    int bl = e / 49, j = e - bl * 49;
    aL[e] = attn[((size_t)(b0 + bl) * 12 + h) * 2401 + i * 49 + j];
  }
  __syncthreads();
  int d = tid & 31, bg = tid >> 5;
  for (int bl = bg; bl < 64; bl += 8) {
    float r = 0.f;
#pragma unroll 7
    for (int j = 0; j < 49; ++j) r += aL[bl * 49 + j] * wf[j * 32 + d];
    size_t oo = ((size_t)(b0 + bl) * 49 + i) * 384 + h * 32 + d;
    o1[oo] = f2b(b2f(o1[oo]) + r);
  }
}

// out[100352x384] = o1(bf16) @ proj_w^T + proj_b, fp32 out.
__global__ __launch_bounds__(256) void k_proj(
    const u16* __restrict__ A, const u16* __restrict__ Bw,
    const float* __restrict__ bias, float* __restrict__ out) {
  int bx = blockIdx.x;
  int mt = bx / 3, nt = bx - mt * 3;
  size_t m0 = (size_t)mt * 128;
  int n0 = nt * 128;
  int tid = threadIdx.x;
  int w = tid >> 6, l = tid & 63;
  int wm = w >> 1, wn = w & 1;
  int lr = l & 15, lg = l >> 4, lk8 = lg << 3;
  __shared__ u16 At[128 * 32];
  __shared__ u16 Bt[128 * 32];
  f32x4 acc[4][4] = {};
  int row = tid >> 2, c8 = (tid & 3) << 3;
  const u16* gA = A + (m0 + row) * 384 + c8;
  const u16* gA2 = A + (m0 + row + 64) * 384 + c8;
  const u16* gB = Bw + (size_t)(n0 + row) * 384 + c8;
  const u16* gB2 = Bw + (size_t)(n0 + row + 64) * 384 + c8;
  for (int ks = 0; ks < 12; ++ks) {
    int k0 = ks * 32;
    async16(At + tid * 8, gA + k0);
    async16(At + (256 + tid) * 8, gA2 + k0);
    async16(Bt + tid * 8, gB + k0);
    async16(Bt + (256 + tid) * 8, gB2 + k0);
    __syncthreads();
    bf16x8 af[4], bfr[4];
#pragma unroll
    for (int mi = 0; mi < 4; ++mi)
      af[mi] = *(const bf16x8*)&At[(wm * 64 + mi * 16 + lr) * 32 + lk8];
#pragma unroll
    for (int ni = 0; ni < 4; ++ni)
      bfr[ni] = *(const bf16x8*)&Bt[(wn * 64 + ni * 16 + lr) * 32 + lk8];
#pragma unroll
    for (int mi = 0; mi < 4; ++mi)
#pragma unroll
      for (int ni = 0; ni < 4; ++ni)
        acc[mi][ni] = __builtin_amdgcn_mfma_f32_16x16x32_bf16(af[mi], bfr[ni], acc[mi][ni], 0, 0, 0);
    __syncthreads();
  }
#pragma unroll
  for (int mi = 0; mi < 4; ++mi)
#pragma unroll
    for (int ni = 0; ni < 4; ++ni)
#pragma unroll
      for (int r = 0; r < 4; ++r) {
        int rr = wm * 64 + mi * 16 + lg * 4 + r;
        int cc = wn * 64 + ni * 16 + lr;
        out[(m0 + rr) * 384 + (size_t)(n0 + cc)] = acc[mi][ni][r] + bias[n0 + cc];
      }
}

extern "C" void kernel_launch(void* const* d_in, const int* in_sizes, int n_in,
                              void* d_out, int out_size, void* d_ws, size_t ws_size,
                              hipStream_t stream) {
  const float* x      = (const float*)d_in[0];
  const float* mask   = (const float*)d_in[1];
  const int*   rpe    = (const int*)d_in[2];
  const float* qkv_w  = (const float*)d_in[3];
  const float* qkv_b  = (const float*)d_in[4];
  const float* proj_w = (const float*)d_in[5];
  const float* proj_b = (const float*)d_in[6];
  const float* q_rpe  = (const float*)d_in[7];
  const float* k_rpe  = (const float*)d_in[8];
  const float* v_rpe  = (const float*)d_in[9];

  float* out  = (float*)d_out;
  float* attn = out + (size_t)100352 * 384;   // output 2 after output 1

  char* ws = (char*)d_ws;
  u16* qkvb   = (u16*)ws;                       // qkv bf16:   231,211,008 B
  u16* wqkvb  = (u16*)(ws + 231211008);         // qkv_w bf16:     884,736 B
  u16* wprojb = (u16*)(ws + 232095744);         // proj_w bf16:    294,912 B
  u16* mbi    = (u16*)(ws + 232390656);         // mask+idx:       307,328 B
  u16* xb     = (u16*)(ws + 232697984);         // x bf16 (dead after k_qkv)
  u16* o1     = xb;                             // reuses xb region: 77,070,336 B (end ~309.8 MB)

  k_cast<<<2048, 256, 0, stream>>>(x, xb, 9633792);
  k_cast<<<432, 256, 0, stream>>>(qkv_w, wqkvb, 110592);
  k_cast<<<144, 256, 0, stream>>>(proj_w, wprojb, 36864);
  k_mbi<<<601, 256, 0, stream>>>(mask, rpe, mbi);
  k_qkv<<<7056, 256, 0, stream>>>(xb, wqkvb, qkv_b, qkvb);
  k_attn<<<6144, 256, 0, stream>>>(qkvb, q_rpe, k_rpe, mbi, attn, o1);
  k_rv<<<18816, 256, 0, stream>>>(attn, rpe, v_rpe, o1);
  k_proj<<<2352, 256, 0, stream>>>(o1, wprojb, proj_b, out);
}

// Round 3
// 646.789 us; speedup vs baseline: 3.1646x; 1.1929x over previous
//
#include <hip/hip_runtime.h>

// SwinTransformerBlock on MI355X (gfx950).
// Pipeline:
//   k_cast x3 : fp32 -> bf16 for x, qkv_w, proj_w
//   k_mbi     : per-window packed table u16 = rpe_idx | (mask!=0)<<8
//   k_qkv     : big MFMA GEMM qkv = x @ qkv_w^T + b (q pre-scaled), bf16 out
//   k_attn    : one WAVE per (b,h): S^T = mfma(K,Q) -> bias/mask gather ->
//               wave-parallel softmax -> attn write (float4) -> P(bf16 LDS) ->
//               O^T = mfma(V^T,P) -> o1 (bf16)
//   k_rv      : MFMA batched GEMM per (h,i): attn(2048x49,bf16) @ v_rpe^T gather,
//               uint2 RMW-add into o1
//   k_proj    : out = o1 @ proj_w^T + proj_b (MFMA 128x128 tiles)

typedef unsigned int u32;
typedef unsigned short u16;
typedef __attribute__((ext_vector_type(8))) short bf16x8;
typedef __attribute__((ext_vector_type(4))) float f32x4;
typedef float f4a __attribute__((ext_vector_type(4), aligned(4)));   // 4B-aligned float4

#define SCALE 0.17677669529663687f   // 32^-0.5

__device__ __forceinline__ u16 f2b(float f) {
  union { float f; u32 u; } c; c.f = f;
  u32 u = c.u;
  return (u16)((u + 0x7FFFu + ((u >> 16) & 1u)) >> 16);   // RNE
}
__device__ __forceinline__ float b2f(u16 s) {
  union { float f; u32 u; } c; c.u = ((u32)s) << 16;
  return c.f;
}
__device__ __forceinline__ void async16(void* lds, const void* g) {
  __builtin_amdgcn_global_load_lds(
      (const __attribute__((address_space(1))) u32*)g,
      (__attribute__((address_space(3))) u32*)lds, 16, 0, 0);
}

__global__ __launch_bounds__(256) void k_cast(const float* __restrict__ s,
                                              u16* __restrict__ d, int n4) {
  int i = blockIdx.x * 256 + threadIdx.x;
  int str = gridDim.x * 256;
  for (; i < n4; i += str) {
    float4 v = ((const float4*)s)[i];
    ushort4 o;
    o.x = f2b(v.x); o.y = f2b(v.y); o.z = f2b(v.z); o.w = f2b(v.w);
    ((ushort4*)d)[i] = o;
  }
}

__global__ __launch_bounds__(256) void k_mbi(const float* __restrict__ mask,
                                             const int* __restrict__ idx,
                                             u16* __restrict__ mbi) {
  int i = blockIdx.x * 256 + threadIdx.x;
  if (i >= 64 * 2401) return;
  int p = i % 2401;
  mbi[i] = (u16)(idx[p] | ((mask[i] != 0.0f) ? 256 : 0));
}

// qkv[100352][1152](bf16) = x[100352][384](bf16) @ qkv_w^T + qkv_b; q cols scaled.
__global__ __launch_bounds__(256) void k_qkv(
    const u16* __restrict__ A, const u16* __restrict__ Bw,
    const float* __restrict__ bias, u16* __restrict__ outq) {
  int bx = blockIdx.x;
  int mt = bx / 9, nt = bx - mt * 9;
  size_t m0 = (size_t)mt * 128;
  int n0 = nt * 128;
  int tid = threadIdx.x;
  int w = tid >> 6, l = tid & 63;
  int wm = w >> 1, wn = w & 1;
  int lr = l & 15, lg = l >> 4, lk8 = lg << 3;
  __shared__ u16 At[128 * 32];
  __shared__ u16 Bt[128 * 32];
  f32x4 acc[4][4] = {};
  int row = tid >> 2, c8 = (tid & 3) << 3;
  const u16* gA = A + (m0 + row) * 384 + c8;
  const u16* gA2 = A + (m0 + row + 64) * 384 + c8;
  const u16* gB = Bw + (size_t)(n0 + row) * 384 + c8;
  const u16* gB2 = Bw + (size_t)(n0 + row + 64) * 384 + c8;
  for (int ks = 0; ks < 12; ++ks) {
    int k0 = ks * 32;
    async16(At + tid * 8, gA + k0);
    async16(At + (256 + tid) * 8, gA2 + k0);
    async16(Bt + tid * 8, gB + k0);
    async16(Bt + (256 + tid) * 8, gB2 + k0);
    __syncthreads();
    bf16x8 af[4], bfr[4];
#pragma unroll
    for (int mi = 0; mi < 4; ++mi)
      af[mi] = *(const bf16x8*)&At[(wm * 64 + mi * 16 + lr) * 32 + lk8];
#pragma unroll
    for (int ni = 0; ni < 4; ++ni)
      bfr[ni] = *(const bf16x8*)&Bt[(wn * 64 + ni * 16 + lr) * 32 + lk8];
#pragma unroll
    for (int mi = 0; mi < 4; ++mi)
#pragma unroll
      for (int ni = 0; ni < 4; ++ni)
        acc[mi][ni] = __builtin_amdgcn_mfma_f32_16x16x32_bf16(af[mi], bfr[ni], acc[mi][ni], 0, 0, 0);
    __syncthreads();
  }
#pragma unroll
  for (int ni = 0; ni < 4; ++ni) {
    int cc = n0 + wn * 64 + ni * 16 + lr;
    float bv = bias[cc];
    float sc = (cc < 384) ? SCALE : 1.0f;
#pragma unroll
    for (int mi = 0; mi < 4; ++mi)
#pragma unroll
      for (int r = 0; r < 4; ++r) {
        size_t rr = m0 + wm * 64 + mi * 16 + lg * 4 + r;
        outq[rr * 1152 + cc] = f2b((acc[mi][ni][r] + bv) * sc);
      }
  }
}

// One WAVE per (b,h); block = 4 waves = heads hg*4..hg*4+3 of one window b.
__global__ __launch_bounds__(256) void k_attn(
    const u16* __restrict__ qkv,
    const float* __restrict__ q_rpe, const float* __restrict__ k_rpe,
    const u16* __restrict__ mbi,
    float* __restrict__ attn, u16* __restrict__ o1) {
  int blk = blockIdx.x;
  int b = blk / 3, hg = blk % 3;
  int tid = threadIdx.x, w = tid >> 6, l = tid & 63;
  int h = hg * 4 + w;
  int lr = l & 15, g = l >> 4;

  __shared__ u16 mbiL[2408];
  __shared__ __align__(16) u16 vL[4][2048];   // [wave][j(64)][d(32)]
  __shared__ __align__(16) u16 pL[4][4096];   // [wave][qi(64)][kj(64)] swizzled
  __shared__ float bqkL[4][172];

  const u16* qbase = qkv + (size_t)b * 49 * 1152 + h * 32;
  const u16* kbase = qbase + 384;
  const u16* vbase = qbase + 768;

  {
    const u16* mrow = mbi + (size_t)(b & 63) * 2401;
    for (int p = tid; p < 2401; p += 256) mbiL[p] = mrow[p];
  }
  // V rows -> LDS (lane-contiguous dest for global_load_lds)
  u16* vw = &vL[w][0];
#pragma unroll
  for (int p = 0; p < 4; ++p) {
    int j = p * 16 + (l >> 2);
    int jr = (j < 49) ? j : 48;
    async16(vw + p * 512 + l * 8, vbase + (size_t)jr * 1152 + (l & 3) * 8);
  }

  bf16x8 qf[4], kf[4];
#pragma unroll
  for (int t = 0; t < 4; ++t) {
    int qi = t * 16 + lr;
    int qir = (qi < 49) ? qi : 48;
    qf[t] = *(const bf16x8*)(qbase + (size_t)qir * 1152 + g * 8);
    kf[t] = *(const bf16x8*)(kbase + (size_t)qir * 1152 + g * 8);
  }

  // S^T[kj][qi]
  f32x4 S[4][4] = {};
#pragma unroll
  for (int mt = 0; mt < 4; ++mt)
#pragma unroll
    for (int nt = 0; nt < 4; ++nt)
      S[mt][nt] = __builtin_amdgcn_mfma_f32_16x16x32_bf16(kf[mt], qf[nt], S[mt][nt], 0, 0, 0);

  // contextual bias table
  {
    float q0d[32], k0d[32];
#pragma unroll
    for (int d = 0; d < 32; ++d) { q0d[d] = b2f(qbase[d]); k0d[d] = b2f(kbase[d]); }
#pragma unroll
    for (int t0 = 0; t0 < 192; t0 += 64) {
      int t = t0 + l;
      if (t < 169) {
        float s = 0.f;
#pragma unroll
        for (int d = 0; d < 32; ++d)
          s += q0d[d] * q_rpe[(h * 32 + d) * 169 + t] +
               k0d[d] * k_rpe[(h * 32 + d) * 169 + t];
        bqkL[w][t] = s;
      }
    }
  }
  __syncthreads();

  // bias + mask (padding -> -1e9)
#pragma unroll
  for (int nt = 0; nt < 4; ++nt) {
    int qi = nt * 16 + lr;
#pragma unroll
    for (int mt = 0; mt < 4; ++mt)
#pragma unroll
      for (int r = 0; r < 4; ++r) {
        int kj = mt * 16 + g * 4 + r;
        float s = S[mt][nt][r];
        if (qi < 49 && kj < 49) {
          u16 t = mbiL[qi * 49 + kj];
          s += bqkL[w][t & 255] - 100.f * (float)(t >> 8);
        } else {
          s = -1e9f;
        }
        S[mt][nt][r] = s;
      }
  }

  // wave-parallel softmax over kj
  float rinv[4];
#pragma unroll
  for (int nt = 0; nt < 4; ++nt) {
    float m = -1e30f;
#pragma unroll
    for (int mt = 0; mt < 4; ++mt)
#pragma unroll
      for (int r = 0; r < 4; ++r) m = fmaxf(m, S[mt][nt][r]);
    m = fmaxf(m, __shfl_xor(m, 16, 64));
    m = fmaxf(m, __shfl_xor(m, 32, 64));
    float sum = 0.f;
#pragma unroll
    for (int mt = 0; mt < 4; ++mt)
#pragma unroll
      for (int r = 0; r < 4; ++r) {
        float e = __expf(S[mt][nt][r] - m);
        S[mt][nt][r] = e;
        sum += e;
      }
    sum += __shfl_xor(sum, 16, 64);
    sum += __shfl_xor(sum, 32, 64);
    rinv[nt] = 1.f / sum;
  }

  // attn output (fp32): 3 float4 (4B-aligned) + 1 scalar per (lane,nt)
  {
    float* ao = attn + (size_t)(b * 12 + h) * 2401;
#pragma unroll
    for (int nt = 0; nt < 4; ++nt) {
      int qi = nt * 16 + lr;
      if (qi < 49) {
        float riv = rinv[nt];
#pragma unroll
        for (int mt = 0; mt < 3; ++mt) {
          f4a vst;
          vst[0] = S[mt][nt][0] * riv;
          vst[1] = S[mt][nt][1] * riv;
          vst[2] = S[mt][nt][2] * riv;
          vst[3] = S[mt][nt][3] * riv;
          *(f4a*)(ao + qi * 49 + mt * 16 + g * 4) = vst;
        }
        if (g == 0) ao[qi * 49 + 48] = S[3][nt][0] * riv;
      }
    }
  }

  // P (unnormalized exp) -> LDS bf16, XOR-swizzled rows
  u16* pw = &pL[w][0];
#pragma unroll
  for (int nt = 0; nt < 4; ++nt) {
    int qi = nt * 16 + lr;
    int swz = (qi & 7) << 4;
#pragma unroll
    for (int mt = 0; mt < 4; ++mt) {
      u32 w0 = (u32)f2b(S[mt][nt][0]) | ((u32)f2b(S[mt][nt][1]) << 16);
      u32 w1 = (u32)f2b(S[mt][nt][2]) | ((u32)f2b(S[mt][nt][3]) << 16);
      int off = (qi * 128 + mt * 32 + g * 8) ^ swz;
      uint2 pk = {w0, w1};
      *(uint2*)((char*)pw + off) = pk;
    }
  }

  // O^T[d][i] = sum_j V^T[d][j] * P[i][j]
  f32x4 O[2][4] = {};
#pragma unroll
  for (int ks = 0; ks < 2; ++ks) {
    bf16x8 pb[4];
#pragma unroll
    for (int nti = 0; nti < 4; ++nti) {
      int qi = nti * 16 + lr;
      int off = (qi * 128 + ks * 64 + g * 16) ^ ((qi & 7) << 4);
      pb[nti] = *(const bf16x8*)((const char*)pw + off);
    }
    bf16x8 va[2];
#pragma unroll
    for (int mtd = 0; mtd < 2; ++mtd)
#pragma unroll
      for (int jj = 0; jj < 8; ++jj)
        va[mtd][jj] = (short)vw[(ks * 32 + g * 8 + jj) * 32 + mtd * 16 + lr];
#pragma unroll
    for (int mtd = 0; mtd < 2; ++mtd)
#pragma unroll
      for (int nti = 0; nti < 4; ++nti)
        O[mtd][nti] = __builtin_amdgcn_mfma_f32_16x16x32_bf16(va[mtd], pb[nti], O[mtd][nti], 0, 0, 0);
  }

  {
    u16* ob = o1 + (size_t)b * 49 * 384 + h * 32;
#pragma unroll
    for (int nti = 0; nti < 4; ++nti) {
      int i = nti * 16 + lr;
      if (i < 49) {
        float riv = rinv[nti];
#pragma unroll
        for (int mtd = 0; mtd < 2; ++mtd) {
          u32 w0 = (u32)f2b(O[mtd][nti][0] * riv) | ((u32)f2b(O[mtd][nti][1] * riv) << 16);
          u32 w1 = (u32)f2b(O[mtd][nti][2] * riv) | ((u32)f2b(O[mtd][nti][3] * riv) << 16);
          uint2 pk = {w0, w1};
          *(uint2*)&ob[(size_t)i * 384 + mtd * 16 + g * 4] = pk;
        }
      }
    }
  }
}

// r_v as MFMA: per (h,i,b-chunk of 256): R[bl,d] = attn_bf16[bl][j] @ wT[d][j]^T.
// M = d (32), N = bl (64/wave), K = j (64, zero-padded past 49).
__global__ __launch_bounds__(256) void k_rv(
    const float* __restrict__ attn, const int* __restrict__ idx,
    const float* __restrict__ v_rpe, u16* __restrict__ o1) {
  int bx = blockIdx.x;
  int bc = bx & 7;
  int hi = bx >> 3;
  int i = hi % 49, h = hi / 49;
  int b0 = bc * 256;
  int tid = threadIdx.x;
  int w = tid >> 6, l = tid & 63;
  int lr = l & 15, g = l >> 4;

  __shared__ __align__(16) u16 aB[256 * 64];   // [bl][j] swizzled (32 KB)
  __shared__ __align__(16) u16 wT[32 * 64];    // [d][j]  swizzled (4 KB)

  // stage wT = (v_rpe[h, idx[i,:], :])^T in bf16, zero for j >= 49
  if (tid < 196) {
    int j = tid >> 2, d0 = (tid & 3) * 8;
    const float* vr = v_rpe + ((size_t)h * 169 + idx[i * 49 + j]) * 32 + d0;
    float4 a = *(const float4*)vr;
    float4 bvv = *(const float4*)(vr + 4);
    float el[8] = {a.x, a.y, a.z, a.w, bvv.x, bvv.y, bvv.z, bvv.w};
#pragma unroll
    for (int e = 0; e < 8; ++e) {
      int d = d0 + e;
      int byte = (d * 128 + j * 2) ^ ((d & 7) << 4);
      *(u16*)((char*)wT + byte) = f2b(el[e]);
    }
  } else {
    int t = tid - 196;                 // 0..59 -> 15 j-rows x 4 d-chunks
    int j = 49 + (t >> 2), d0 = (t & 3) * 8;
#pragma unroll
    for (int e = 0; e < 8; ++e) {
      int d = d0 + e;
      int byte = (d * 128 + j * 2) ^ ((d & 7) << 4);
      *(u16*)((char*)wT + byte) = 0;
    }
  }

  // stage aB: one attn row per thread (49 floats, 4B-aligned), bf16, j>=49 zero
  {
    int bl = tid;
    const float* ar = attn + ((size_t)(b0 + bl) * 12 + h) * 2401 + (size_t)i * 49;
    f4a fv[12];
#pragma unroll
    for (int q = 0; q < 12; ++q) fv[q] = *(const f4a*)(ar + q * 4);
    float tail = ar[48];
    u32 wd[32];
#pragma unroll
    for (int k = 0; k < 24; ++k)
      wd[k] = (u32)f2b(fv[k >> 1][(k & 1) * 2]) |
              ((u32)f2b(fv[k >> 1][(k & 1) * 2 + 1]) << 16);
    wd[24] = (u32)f2b(tail);
#pragma unroll
    for (int k = 25; k < 32; ++k) wd[k] = 0;
#pragma unroll
    for (int q = 0; q < 8; ++q) {
      int byte = (bl * 128 + q * 16) ^ ((bl & 7) << 4);
      *(uint4*)((char*)aB + byte) = *(uint4*)&wd[q * 4];
    }
  }
  __syncthreads();

  // MFMA: acc[mt(d-tile)][nt(bl-tile)]
  f32x4 acc[2][4] = {};
#pragma unroll
  for (int ks = 0; ks < 2; ++ks) {
    bf16x8 af[2], bfr[4];
#pragma unroll
    for (int mt = 0; mt < 2; ++mt) {
      int d = mt * 16 + lr;
      int byte = (d * 128 + ks * 64 + g * 16) ^ ((d & 7) << 4);
      af[mt] = *(const bf16x8*)((const char*)wT + byte);
    }
#pragma unroll
    for (int nt = 0; nt < 4; ++nt) {
      int row = w * 64 + nt * 16 + lr;
      int byte = (row * 128 + ks * 64 + g * 16) ^ ((row & 7) << 4);
      bfr[nt] = *(const bf16x8*)((const char*)aB + byte);
    }
#pragma unroll
    for (int mt = 0; mt < 2; ++mt)
#pragma unroll
      for (int nt = 0; nt < 4; ++nt)
        acc[mt][nt] = __builtin_amdgcn_mfma_f32_16x16x32_bf16(af[mt], bfr[nt], acc[mt][nt], 0, 0, 0);
  }

  // RMW epilogue: 4 consecutive d per (mt,nt) -> uint2
#pragma unroll
  for (int nt = 0; nt < 4; ++nt) {
    int bl = w * 64 + nt * 16 + lr;
    u16* ob = o1 + ((size_t)(b0 + bl) * 49 + i) * 384 + h * 32;
#pragma unroll
    for (int mt = 0; mt < 2; ++mt) {
      int d = mt * 16 + g * 4;
      uint2 old = *(uint2*)&ob[d];
      uint2 nw;
      nw.x = (u32)f2b(b2f((u16)(old.x & 0xffff)) + acc[mt][nt][0]) |
             ((u32)f2b(b2f((u16)(old.x >> 16)) + acc[mt][nt][1]) << 16);
      nw.y = (u32)f2b(b2f((u16)(old.y & 0xffff)) + acc[mt][nt][2]) |
             ((u32)f2b(b2f((u16)(old.y >> 16)) + acc[mt][nt][3]) << 16);
      *(uint2*)&ob[d] = nw;
    }
  }
}

// out[100352x384] = o1(bf16) @ proj_w^T + proj_b, fp32 out.
__global__ __launch_bounds__(256) void k_proj(
    const u16* __restrict__ A, const u16* __restrict__ Bw,
    const float* __restrict__ bias, float* __restrict__ out) {
  int bx = blockIdx.x;
  int mt = bx / 3, nt = bx - mt * 3;
  size_t m0 = (size_t)mt * 128;
  int n0 = nt * 128;
  int tid = threadIdx.x;
  int w = tid >> 6, l = tid & 63;
  int wm = w >> 1, wn = w & 1;
  int lr = l & 15, lg = l >> 4, lk8 = lg << 3;
  __shared__ u16 At[128 * 32];
  __shared__ u16 Bt[128 * 32];
  f32x4 acc[4][4] = {};
  int row = tid >> 2, c8 = (tid & 3) << 3;
  const u16* gA = A + (m0 + row) * 384 + c8;
  const u16* gA2 = A + (m0 + row + 64) * 384 + c8;
  const u16* gB = Bw + (size_t)(n0 + row) * 384 + c8;
  const u16* gB2 = Bw + (size_t)(n0 + row + 64) * 384 + c8;
  for (int ks = 0; ks < 12; ++ks) {
    int k0 = ks * 32;
    async16(At + tid * 8, gA + k0);
    async16(At + (256 + tid) * 8, gA2 + k0);
    async16(Bt + tid * 8, gB + k0);
    async16(Bt + (256 + tid) * 8, gB2 + k0);
    __syncthreads();
    bf16x8 af[4], bfr[4];
#pragma unroll
    for (int mi = 0; mi < 4; ++mi)
      af[mi] = *(const bf16x8*)&At[(wm * 64 + mi * 16 + lr) * 32 + lk8];
#pragma unroll
    for (int ni = 0; ni < 4; ++ni)
      bfr[ni] = *(const bf16x8*)&Bt[(wn * 64 + ni * 16 + lr) * 32 + lk8];
#pragma unroll
    for (int mi = 0; mi < 4; ++mi)
#pragma unroll
      for (int ni = 0; ni < 4; ++ni)
        acc[mi][ni] = __builtin_amdgcn_mfma_f32_16x16x32_bf16(af[mi], bfr[ni], acc[mi][ni], 0, 0, 0);
    __syncthreads();
  }
#pragma unroll
  for (int mi = 0; mi < 4; ++mi)
#pragma unroll
    for (int ni = 0; ni < 4; ++ni)
#pragma unroll
      for (int r = 0; r < 4; ++r) {
        int rr = wm * 64 + mi * 16 + lg * 4 + r;
        int cc = wn * 64 + ni * 16 + lr;
        out[(m0 + rr) * 384 + (size_t)(n0 + cc)] = acc[mi][ni][r] + bias[n0 + cc];
      }
}

extern "C" void kernel_launch(void* const* d_in, const int* in_sizes, int n_in,
                              void* d_out, int out_size, void* d_ws, size_t ws_size,
                              hipStream_t stream) {
  const float* x      = (const float*)d_in[0];
  const float* mask   = (const float*)d_in[1];
  const int*   rpe    = (const int*)d_in[2];
  const float* qkv_w  = (const float*)d_in[3];
  const float* qkv_b  = (const float*)d_in[4];
  const float* proj_w = (const float*)d_in[5];
  const float* proj_b = (const float*)d_in[6];
  const float* q_rpe  = (const float*)d_in[7];
  const float* k_rpe  = (const float*)d_in[8];
  const float* v_rpe  = (const float*)d_in[9];

  float* out  = (float*)d_out;
  float* attn = out + (size_t)100352 * 384;   // output 2 after output 1

  char* ws = (char*)d_ws;
  u16* qkvb   = (u16*)ws;                       // qkv bf16:   231,211,008 B
  u16* wqkvb  = (u16*)(ws + 231211008);         // qkv_w bf16:     884,736 B
  u16* wprojb = (u16*)(ws + 232095744);         // proj_w bf16:    294,912 B
  u16* mbi    = (u16*)(ws + 232390656);         // mask+idx:       307,328 B
  u16* xb     = (u16*)(ws + 232697984);         // x bf16 (dead after k_qkv)
  u16* o1     = xb;                             // reuses xb region

  k_cast<<<2048, 256, 0, stream>>>(x, xb, 9633792);
  k_cast<<<432, 256, 0, stream>>>(qkv_w, wqkvb, 110592);
  k_cast<<<144, 256, 0, stream>>>(proj_w, wprojb, 36864);
  k_mbi<<<601, 256, 0, stream>>>(mask, rpe, mbi);
  k_qkv<<<7056, 256, 0, stream>>>(xb, wqkvb, qkv_b, qkvb);
  k_attn<<<6144, 256, 0, stream>>>(qkvb, q_rpe, k_rpe, mbi, attn, o1);
  k_rv<<<4704, 256, 0, stream>>>(attn, rpe, v_rpe, o1);
  k_proj<<<2352, 256, 0, stream>>>(o1, wprojb, proj_b, out);
}

// Round 4
// 589.202 us; speedup vs baseline: 3.4739x; 1.0977x over previous
//
#include <hip/hip_runtime.h>

// SwinTransformerBlock on MI355X (gfx950).
// Pipeline:
//   k_cast x3 : fp32 -> bf16 for x, qkv_w, proj_w
//   k_mbi     : per-window packed table u16 = rpe_idx | (mask!=0)<<8
//   k_qkv     : big MFMA GEMM qkv = x @ qkv_w^T + b (q pre-scaled), bf16 out
//   k_bqk     : bqk[b,h,t] = q0.q_rpe + k0.k_rpe as MFMA GEMM (M=b,N=t,K=64)
//   k_attn    : one WAVE per (b,h): S^T = mfma(K,Q) -> bias/mask gather ->
//               wave-parallel softmax -> P(bf16 LDS) -> O^T = mfma(V^T,P)
//               -> o1; attn written via LDS staging, coalesced dword stores
//   k_rv      : MFMA batched GEMM per (h,i): attn(bf16) @ v_rpe^T gather, RMW o1
//   k_proj    : out = o1 @ proj_w^T + proj_b (MFMA 128x128 tiles)

typedef unsigned int u32;
typedef unsigned short u16;
typedef __attribute__((ext_vector_type(8))) short bf16x8;
typedef __attribute__((ext_vector_type(4))) float f32x4;
typedef float f4a __attribute__((ext_vector_type(4), aligned(4)));

#define SCALE 0.17677669529663687f   // 32^-0.5

__device__ __forceinline__ u16 f2b(float f) {
  union { float f; u32 u; } c; c.f = f;
  u32 u = c.u;
  return (u16)((u + 0x7FFFu + ((u >> 16) & 1u)) >> 16);   // RNE
}
__device__ __forceinline__ float b2f(u16 s) {
  union { float f; u32 u; } c; c.u = ((u32)s) << 16;
  return c.f;
}
__device__ __forceinline__ void async16(void* lds, const void* g) {
  __builtin_amdgcn_global_load_lds(
      (const __attribute__((address_space(1))) u32*)g,
      (__attribute__((address_space(3))) u32*)lds, 16, 0, 0);
}

__global__ __launch_bounds__(256) void k_cast(const float* __restrict__ s,
                                              u16* __restrict__ d, int n4) {
  int i = blockIdx.x * 256 + threadIdx.x;
  int str = gridDim.x * 256;
  for (; i < n4; i += str) {
    float4 v = ((const float4*)s)[i];
    ushort4 o;
    o.x = f2b(v.x); o.y = f2b(v.y); o.z = f2b(v.z); o.w = f2b(v.w);
    ((ushort4*)d)[i] = o;
  }
}

__global__ __launch_bounds__(256) void k_mbi(const float* __restrict__ mask,
                                             const int* __restrict__ idx,
                                             u16* __restrict__ mbi) {
  int i = blockIdx.x * 256 + threadIdx.x;
  if (i >= 64 * 2401) return;
  int p = i % 2401;
  mbi[i] = (u16)(idx[p] | ((mask[i] != 0.0f) ? 256 : 0));
}

// qkv[100352][1152](bf16) = x @ qkv_w^T + qkv_b; q cols scaled.
__global__ __launch_bounds__(256) void k_qkv(
    const u16* __restrict__ A, const u16* __restrict__ Bw,
    const float* __restrict__ bias, u16* __restrict__ outq) {
  int bx = blockIdx.x;
  int mt = bx / 9, nt = bx - mt * 9;
  size_t m0 = (size_t)mt * 128;
  int n0 = nt * 128;
  int tid = threadIdx.x;
  int w = tid >> 6, l = tid & 63;
  int wm = w >> 1, wn = w & 1;
  int lr = l & 15, lg = l >> 4, lk8 = lg << 3;
  __shared__ u16 At[128 * 32];
  __shared__ u16 Bt[128 * 32];
  f32x4 acc[4][4] = {};
  int row = tid >> 2, c8 = (tid & 3) << 3;
  const u16* gA = A + (m0 + row) * 384 + c8;
  const u16* gA2 = A + (m0 + row + 64) * 384 + c8;
  const u16* gB = Bw + (size_t)(n0 + row) * 384 + c8;
  const u16* gB2 = Bw + (size_t)(n0 + row + 64) * 384 + c8;
  for (int ks = 0; ks < 12; ++ks) {
    int k0 = ks * 32;
    async16(At + tid * 8, gA + k0);
    async16(At + (256 + tid) * 8, gA2 + k0);
    async16(Bt + tid * 8, gB + k0);
    async16(Bt + (256 + tid) * 8, gB2 + k0);
    __syncthreads();
    bf16x8 af[4], bfr[4];
#pragma unroll
    for (int mi = 0; mi < 4; ++mi)
      af[mi] = *(const bf16x8*)&At[(wm * 64 + mi * 16 + lr) * 32 + lk8];
#pragma unroll
    for (int ni = 0; ni < 4; ++ni)
      bfr[ni] = *(const bf16x8*)&Bt[(wn * 64 + ni * 16 + lr) * 32 + lk8];
#pragma unroll
    for (int mi = 0; mi < 4; ++mi)
#pragma unroll
      for (int ni = 0; ni < 4; ++ni)
        acc[mi][ni] = __builtin_amdgcn_mfma_f32_16x16x32_bf16(af[mi], bfr[ni], acc[mi][ni], 0, 0, 0);
    __syncthreads();
  }
#pragma unroll
  for (int ni = 0; ni < 4; ++ni) {
    int cc = n0 + wn * 64 + ni * 16 + lr;
    float bv = bias[cc];
    float sc = (cc < 384) ? SCALE : 1.0f;
#pragma unroll
    for (int mi = 0; mi < 4; ++mi)
#pragma unroll
      for (int r = 0; r < 4; ++r) {
        size_t rr = m0 + wm * 64 + mi * 16 + lg * 4 + r;
        outq[rr * 1152 + cc] = f2b((acc[mi][ni][r] + bv) * sc);
      }
  }
}

// bqk[b][h][t] = sum_d q0[b,h,d]*q_rpe[h,d,t] + k0[b,h,d]*k_rpe[h,d,t]
// MFMA: M=64 b's per block, N=192 (t, 169 valid), K=64 (q|k concat).
__global__ __launch_bounds__(256) void k_bqk(
    const u16* __restrict__ qkv, const float* __restrict__ q_rpe,
    const float* __restrict__ k_rpe, float* __restrict__ bqk) {
  int bx = blockIdx.x;
  int mtile = bx / 12, h = bx % 12;
  int b0 = mtile * 64;
  int tid = threadIdx.x;
  int w = tid >> 6, l = tid & 63;
  int lr = l & 15, g = l >> 4;

  __shared__ __align__(16) u16 At[64 * 64];    // [m][k] swizzled, 8 KB
  __shared__ __align__(16) u16 Bt[192 * 64];   // [t][k] swizzled, 24 KB

  // A: rows = windows b0+m, K = [q0(32) | k0(32)] at token 0
  {
    int m = tid >> 2;
#pragma unroll
    for (int rnd = 0; rnd < 2; ++rnd) {
      int c = (tid & 3) + rnd * 4;
      const u16* src = qkv + (size_t)(b0 + m) * 56448 + h * 32 +
                       ((c < 4) ? c * 8 : 384 + (c - 4) * 8);
      bf16x8 v = *(const bf16x8*)src;
      int byte = (m * 128 + c * 16) ^ ((m & 7) << 4);
      *(bf16x8*)((char*)At + byte) = v;
    }
  }
  // B: rows = t, K = [q_rpe(d) | k_rpe(d)] columns at t
  if (tid < 192) {
    int t = tid;
#pragma unroll
    for (int c = 0; c < 8; ++c) {
      u16 pk[8];
#pragma unroll
      for (int e = 0; e < 8; ++e) {
        int d = (c & 3) * 8 + e;
        float v = 0.f;
        if (t < 169)
          v = (c < 4) ? q_rpe[(h * 32 + d) * 169 + t]
                      : k_rpe[(h * 32 + d) * 169 + t];
        pk[e] = f2b(v);
      }
      int byte = (t * 128 + c * 16) ^ ((t & 7) << 4);
      *(bf16x8*)((char*)Bt + byte) = *(bf16x8*)pk;
    }
  }
  __syncthreads();

  f32x4 acc[12] = {};
  bf16x8 af[2];
#pragma unroll
  for (int ks = 0; ks < 2; ++ks) {
    int row = w * 16 + lr;
    af[ks] = *(const bf16x8*)((const char*)At +
              ((row * 128 + ks * 64 + g * 16) ^ ((row & 7) << 4)));
  }
#pragma unroll
  for (int nt = 0; nt < 12; ++nt) {
#pragma unroll
    for (int ks = 0; ks < 2; ++ks) {
      int t = nt * 16 + lr;
      bf16x8 bf = *(const bf16x8*)((const char*)Bt +
                   ((t * 128 + ks * 64 + g * 16) ^ ((t & 7) << 4)));
      acc[nt] = __builtin_amdgcn_mfma_f32_16x16x32_bf16(af[ks], bf, acc[nt], 0, 0, 0);
    }
  }
#pragma unroll
  for (int nt = 0; nt < 12; ++nt) {
    int t = nt * 16 + lr;
    if (t < 169) {
#pragma unroll
      for (int r = 0; r < 4; ++r) {
        int b = b0 + w * 16 + g * 4 + r;
        bqk[((size_t)b * 12 + h) * 169 + t] = acc[nt][r];
      }
    }
  }
}

// One WAVE per (b,h); block = 4 waves = heads hg*4..hg*4+3 of window b.
__global__ __launch_bounds__(256) void k_attn(
    const u16* __restrict__ qkv, const float* __restrict__ bqkG,
    const u16* __restrict__ mbi,
    float* __restrict__ attn, u16* __restrict__ o1) {
  int blk = blockIdx.x;
  int b = blk / 3, hg = blk % 3;
  int tid = threadIdx.x, w = tid >> 6, l = tid & 63;
  int h = hg * 4 + w;
  int lr = l & 15, g = l >> 4;

  __shared__ __align__(16) char R[32704];      // union region
  __shared__ __align__(16) u16 vL[4][2048];    // [wave][j(64)][d(32)]
  u16* mbiL = (u16*)R;                         // [2408]
  float* bqkL = (float*)(R + 4832);            // [4][172]
  u16* pL = (u16*)(R + 7600);                  // [4][49*64]
  float* aS = (float*)R;                       // [4][1216] (post-PV overlay)

  const u16* qbase = qkv + (size_t)b * 49 * 1152 + h * 32;
  const u16* kbase = qbase + 384;
  const u16* vbase = qbase + 768;

  {
    const u16* mrow = mbi + (size_t)(b & 63) * 2401;
    for (int p = tid; p < 2401; p += 256) mbiL[p] = mrow[p];
  }
  // V rows -> LDS (lane-contiguous dest for global_load_lds)
  u16* vw = &vL[w][0];
#pragma unroll
  for (int p = 0; p < 4; ++p) {
    int j = p * 16 + (l >> 2);
    int jr = (j < 49) ? j : 48;
    async16(vw + p * 512 + l * 8, vbase + (size_t)jr * 1152 + (l & 3) * 8);
  }
  // bqk row for this (b,h)
  {
    const float* bg = bqkG + ((size_t)b * 12 + h) * 169;
#pragma unroll
    for (int t0 = 0; t0 < 192; t0 += 64) {
      int t = t0 + l;
      if (t < 169) bqkL[w * 172 + t] = bg[t];
    }
  }

  bf16x8 qf[4], kf[4];
#pragma unroll
  for (int t = 0; t < 4; ++t) {
    int qi = t * 16 + lr;
    int qir = (qi < 49) ? qi : 48;
    qf[t] = *(const bf16x8*)(qbase + (size_t)qir * 1152 + g * 8);
    kf[t] = *(const bf16x8*)(kbase + (size_t)qir * 1152 + g * 8);
  }

  // S^T[kj][qi]
  f32x4 S[4][4] = {};
#pragma unroll
  for (int mt = 0; mt < 4; ++mt)
#pragma unroll
    for (int nt = 0; nt < 4; ++nt)
      S[mt][nt] = __builtin_amdgcn_mfma_f32_16x16x32_bf16(kf[mt], qf[nt], S[mt][nt], 0, 0, 0);

  __syncthreads();   // mbiL + vL (drains vmcnt); bqkL own-wave

  // bias + mask (padding -> -1e9)
#pragma unroll
  for (int nt = 0; nt < 4; ++nt) {
    int qi = nt * 16 + lr;
#pragma unroll
    for (int mt = 0; mt < 4; ++mt)
#pragma unroll
      for (int r = 0; r < 4; ++r) {
        int kj = mt * 16 + g * 4 + r;
        float s = S[mt][nt][r];
        if (qi < 49 && kj < 49) {
          u16 t = mbiL[qi * 49 + kj];
          s += bqkL[w * 172 + (t & 255)] - 100.f * (float)(t >> 8);
        } else {
          s = -1e9f;
        }
        S[mt][nt][r] = s;
      }
  }

  // wave-parallel softmax over kj
  float rinv[4];
#pragma unroll
  for (int nt = 0; nt < 4; ++nt) {
    float m = -1e30f;
#pragma unroll
    for (int mt = 0; mt < 4; ++mt)
#pragma unroll
      for (int r = 0; r < 4; ++r) m = fmaxf(m, S[mt][nt][r]);
    m = fmaxf(m, __shfl_xor(m, 16, 64));
    m = fmaxf(m, __shfl_xor(m, 32, 64));
    float sum = 0.f;
#pragma unroll
    for (int mt = 0; mt < 4; ++mt)
#pragma unroll
      for (int r = 0; r < 4; ++r) {
        float e = __expf(S[mt][nt][r] - m);
        S[mt][nt][r] = e;
        sum += e;
      }
    sum += __shfl_xor(sum, 16, 64);
    sum += __shfl_xor(sum, 32, 64);
    rinv[nt] = 1.f / sum;
  }

  // P (unnormalized exp) -> LDS bf16, XOR-swizzled rows (49 rows/wave)
  u16* pw = pL + w * 3136;
#pragma unroll
  for (int nt = 0; nt < 4; ++nt) {
    int qi = nt * 16 + lr;
    if (qi < 49) {
      int swz = (qi & 7) << 4;
#pragma unroll
      for (int mt = 0; mt < 4; ++mt) {
        u32 w0 = (u32)f2b(S[mt][nt][0]) | ((u32)f2b(S[mt][nt][1]) << 16);
        u32 w1 = (u32)f2b(S[mt][nt][2]) | ((u32)f2b(S[mt][nt][3]) << 16);
        int off = (qi * 128 + mt * 32 + g * 8) ^ swz;
        uint2 pk = {w0, w1};
        *(uint2*)((char*)pw + off) = pk;
      }
    }
  }

  // O^T[d][i] = sum_j V^T[d][j] * P[i][j]
  f32x4 O[2][4] = {};
#pragma unroll
  for (int ks = 0; ks < 2; ++ks) {
    bf16x8 pb[4];
#pragma unroll
    for (int nti = 0; nti < 4; ++nti) {
      int qi = nti * 16 + lr;
      int qir = (qi < 49) ? qi : 48;
      int off = (qir * 128 + ks * 64 + g * 16) ^ ((qir & 7) << 4);
      pb[nti] = *(const bf16x8*)((const char*)pw + off);
    }
    bf16x8 va[2];
#pragma unroll
    for (int mtd = 0; mtd < 2; ++mtd)
#pragma unroll
      for (int jj = 0; jj < 8; ++jj)
        va[mtd][jj] = (short)vw[(ks * 32 + g * 8 + jj) * 32 + mtd * 16 + lr];
#pragma unroll
    for (int mtd = 0; mtd < 2; ++mtd)
#pragma unroll
      for (int nti = 0; nti < 4; ++nti)
        O[mtd][nti] = __builtin_amdgcn_mfma_f32_16x16x32_bf16(va[mtd], pb[nti], O[mtd][nti], 0, 0, 0);
  }

  // store o1 (bf16)
  {
    u16* ob = o1 + (size_t)b * 49 * 384 + h * 32;
#pragma unroll
    for (int nti = 0; nti < 4; ++nti) {
      int i = nti * 16 + lr;
      if (i < 49) {
        float riv = rinv[nti];
#pragma unroll
        for (int mtd = 0; mtd < 2; ++mtd) {
          u32 w0 = (u32)f2b(O[mtd][nti][0] * riv) | ((u32)f2b(O[mtd][nti][1] * riv) << 16);
          u32 w1 = (u32)f2b(O[mtd][nti][2] * riv) | ((u32)f2b(O[mtd][nti][3] * riv) << 16);
          uint2 pk = {w0, w1};
          *(uint2*)&ob[(size_t)i * 384 + mtd * 16 + g * 4] = pk;
        }
      }
    }
  }

  // attn output: stage normalized rows in LDS (overlay), stream coalesced.
  __syncthreads();   // all PV reads of pL complete before overlay
  float* aw = aS + w * 1216;
  float* ao = attn + (size_t)(b * 12 + h) * 2401;
#pragma unroll
  for (int half = 0; half < 2; ++half) {
    int lo = half * 1204;
#pragma unroll
    for (int nt = 0; nt < 4; ++nt) {
      int qi = nt * 16 + lr;
      if (qi < 49) {
        float riv = rinv[nt];
#pragma unroll
        for (int mt = 0; mt < 4; ++mt)
#pragma unroll
          for (int r = 0; r < 4; ++r) {
            int kj = mt * 16 + g * 4 + r;
            if (kj < 49) {
              int p = qi * 49 + kj - lo;
              if (p >= 0 && p < 1204) aw[p] = S[mt][nt][r] * riv;
            }
          }
      }
    }
    asm volatile("s_waitcnt lgkmcnt(0)" ::: "memory");
    int lim = half ? 1197 : 1204;
#pragma unroll
    for (int it = 0; it < 19; ++it) {
      int p = l + it * 64;
      if (p < lim) ao[lo + p] = aw[p];
    }
    asm volatile("s_waitcnt lgkmcnt(0)" ::: "memory");
  }
}

// r_v as MFMA: per (h,i,b-chunk of 256): R[bl,d] = attn_bf16[bl][j] @ wT[d][j]^T.
__global__ __launch_bounds__(256) void k_rv(
    const float* __restrict__ attn, const int* __restrict__ idx,
    const float* __restrict__ v_rpe, u16* __restrict__ o1) {
  int bx = blockIdx.x;
  int bc = bx & 7;
  int hi = bx >> 3;
  int i = hi % 49, h = hi / 49;
  int b0 = bc * 256;
  int tid = threadIdx.x;
  int w = tid >> 6, l = tid & 63;
  int lr = l & 15, g = l >> 4;

  __shared__ __align__(16) u16 aB[256 * 64];
  __shared__ __align__(16) u16 wT[32 * 64];

  if (tid < 196) {
    int j = tid >> 2, d0 = (tid & 3) * 8;
    const float* vr = v_rpe + ((size_t)h * 169 + idx[i * 49 + j]) * 32 + d0;
    float4 a = *(const float4*)vr;
    float4 bvv = *(const float4*)(vr + 4);
    float el[8] = {a.x, a.y, a.z, a.w, bvv.x, bvv.y, bvv.z, bvv.w};
#pragma unroll
    for (int e = 0; e < 8; ++e) {
      int d = d0 + e;
      int byte = (d * 128 + j * 2) ^ ((d & 7) << 4);
      *(u16*)((char*)wT + byte) = f2b(el[e]);
    }
  } else {
    int t = tid - 196;
    int j = 49 + (t >> 2), d0 = (t & 3) * 8;
#pragma unroll
    for (int e = 0; e < 8; ++e) {
      int d = d0 + e;
      int byte = (d * 128 + j * 2) ^ ((d & 7) << 4);
      *(u16*)((char*)wT + byte) = 0;
    }
  }

  {
    int bl = tid;
    const float* ar = attn + ((size_t)(b0 + bl) * 12 + h) * 2401 + (size_t)i * 49;
    f4a fv[12];
#pragma unroll
    for (int q = 0; q < 12; ++q) fv[q] = *(const f4a*)(ar + q * 4);
    float tail = ar[48];
    u32 wd[32];
#pragma unroll
    for (int k = 0; k < 24; ++k)
      wd[k] = (u32)f2b(fv[k >> 1][(k & 1) * 2]) |
              ((u32)f2b(fv[k >> 1][(k & 1) * 2 + 1]) << 16);
    wd[24] = (u32)f2b(tail);
#pragma unroll
    for (int k = 25; k < 32; ++k) wd[k] = 0;
#pragma unroll
    for (int q = 0; q < 8; ++q) {
      int byte = (bl * 128 + q * 16) ^ ((bl & 7) << 4);
      *(uint4*)((char*)aB + byte) = *(uint4*)&wd[q * 4];
    }
  }
  __syncthreads();

  f32x4 acc[2][4] = {};
#pragma unroll
  for (int ks = 0; ks < 2; ++ks) {
    bf16x8 af[2], bfr[4];
#pragma unroll
    for (int mt = 0; mt < 2; ++mt) {
      int d = mt * 16 + lr;
      int byte = (d * 128 + ks * 64 + g * 16) ^ ((d & 7) << 4);
      af[mt] = *(const bf16x8*)((const char*)wT + byte);
    }
#pragma unroll
    for (int nt = 0; nt < 4; ++nt) {
      int row = w * 64 + nt * 16 + lr;
      int byte = (row * 128 + ks * 64 + g * 16) ^ ((row & 7) << 4);
      bfr[nt] = *(const bf16x8*)((const char*)aB + byte);
    }
#pragma unroll
    for (int mt = 0; mt < 2; ++mt)
#pragma unroll
      for (int nt = 0; nt < 4; ++nt)
        acc[mt][nt] = __builtin_amdgcn_mfma_f32_16x16x32_bf16(af[mt], bfr[nt], acc[mt][nt], 0, 0, 0);
  }

#pragma unroll
  for (int nt = 0; nt < 4; ++nt) {
    int bl = w * 64 + nt * 16 + lr;
    u16* ob = o1 + ((size_t)(b0 + bl) * 49 + i) * 384 + h * 32;
#pragma unroll
    for (int mt = 0; mt < 2; ++mt) {
      int d = mt * 16 + g * 4;
      uint2 old = *(uint2*)&ob[d];
      uint2 nw;
      nw.x = (u32)f2b(b2f((u16)(old.x & 0xffff)) + acc[mt][nt][0]) |
             ((u32)f2b(b2f((u16)(old.x >> 16)) + acc[mt][nt][1]) << 16);
      nw.y = (u32)f2b(b2f((u16)(old.y & 0xffff)) + acc[mt][nt][2]) |
             ((u32)f2b(b2f((u16)(old.y >> 16)) + acc[mt][nt][3]) << 16);
      *(uint2*)&ob[d] = nw;
    }
  }
}

// out[100352x384] = o1(bf16) @ proj_w^T + proj_b, fp32 out.
__global__ __launch_bounds__(256) void k_proj(
    const u16* __restrict__ A, const u16* __restrict__ Bw,
    const float* __restrict__ bias, float* __restrict__ out) {
  int bx = blockIdx.x;
  int mt = bx / 3, nt = bx - mt * 3;
  size_t m0 = (size_t)mt * 128;
  int n0 = nt * 128;
  int tid = threadIdx.x;
  int w = tid >> 6, l = tid & 63;
  int wm = w >> 1, wn = w & 1;
  int lr = l & 15, lg = l >> 4, lk8 = lg << 3;
  __shared__ u16 At[128 * 32];
  __shared__ u16 Bt[128 * 32];
  f32x4 acc[4][4] = {};
  int row = tid >> 2, c8 = (tid & 3) << 3;
  const u16* gA = A + (m0 + row) * 384 + c8;
  const u16* gA2 = A + (m0 + row + 64) * 384 + c8;
  const u16* gB = Bw + (size_t)(n0 + row) * 384 + c8;
  const u16* gB2 = Bw + (size_t)(n0 + row + 64) * 384 + c8;
  for (int ks = 0; ks < 12; ++ks) {
    int k0 = ks * 32;
    async16(At + tid * 8, gA + k0);
    async16(At + (256 + tid) * 8, gA2 + k0);
    async16(Bt + tid * 8, gB + k0);
    async16(Bt + (256 + tid) * 8, gB2 + k0);
    __syncthreads();
    bf16x8 af[4], bfr[4];
#pragma unroll
    for (int mi = 0; mi < 4; ++mi)
      af[mi] = *(const bf16x8*)&At[(wm * 64 + mi * 16 + lr) * 32 + lk8];
#pragma unroll
    for (int ni = 0; ni < 4; ++ni)
      bfr[ni] = *(const bf16x8*)&Bt[(wn * 64 + ni * 16 + lr) * 32 + lk8];
#pragma unroll
    for (int mi = 0; mi < 4; ++mi)
#pragma unroll
      for (int ni = 0; ni < 4; ++ni)
        acc[mi][ni] = __builtin_amdgcn_mfma_f32_16x16x32_bf16(af[mi], bfr[ni], acc[mi][ni], 0, 0, 0);
    __syncthreads();
  }
#pragma unroll
  for (int mi = 0; mi < 4; ++mi)
#pragma unroll
    for (int ni = 0; ni < 4; ++ni)
#pragma unroll
      for (int r = 0; r < 4; ++r) {
        int rr = wm * 64 + mi * 16 + lg * 4 + r;
        int cc = wn * 64 + ni * 16 + lr;
        out[(m0 + rr) * 384 + (size_t)(n0 + cc)] = acc[mi][ni][r] + bias[n0 + cc];
      }
}

extern "C" void kernel_launch(void* const* d_in, const int* in_sizes, int n_in,
                              void* d_out, int out_size, void* d_ws, size_t ws_size,
                              hipStream_t stream) {
  const float* x      = (const float*)d_in[0];
  const float* mask   = (const float*)d_in[1];
  const int*   rpe    = (const int*)d_in[2];
  const float* qkv_w  = (const float*)d_in[3];
  const float* qkv_b  = (const float*)d_in[4];
  const float* proj_w = (const float*)d_in[5];
  const float* proj_b = (const float*)d_in[6];
  const float* q_rpe  = (const float*)d_in[7];
  const float* k_rpe  = (const float*)d_in[8];
  const float* v_rpe  = (const float*)d_in[9];

  float* out  = (float*)d_out;
  float* attn = out + (size_t)100352 * 384;   // output 2 after output 1
  float* bqkG = out;                           // scratch in out region (k_proj overwrites last)

  char* ws = (char*)d_ws;
  u16* qkvb   = (u16*)ws;                       // qkv bf16:   231,211,008 B
  u16* wqkvb  = (u16*)(ws + 231211008);         // qkv_w bf16
  u16* wprojb = (u16*)(ws + 232095744);         // proj_w bf16
  u16* mbi    = (u16*)(ws + 232390656);         // mask+idx
  u16* xb     = (u16*)(ws + 232697984);         // x bf16 (dead after k_qkv)
  u16* o1     = xb;                             // reuses xb region

  k_cast<<<2048, 256, 0, stream>>>(x, xb, 9633792);
  k_cast<<<432, 256, 0, stream>>>(qkv_w, wqkvb, 110592);
  k_cast<<<144, 256, 0, stream>>>(proj_w, wprojb, 36864);
  k_mbi<<<601, 256, 0, stream>>>(mask, rpe, mbi);
  k_qkv<<<7056, 256, 0, stream>>>(xb, wqkvb, qkv_b, qkvb);
  k_bqk<<<384, 256, 0, stream>>>(qkvb, q_rpe, k_rpe, bqkG);
  k_attn<<<6144, 256, 0, stream>>>(qkvb, bqkG, mbi, attn, o1);
  k_rv<<<4704, 256, 0, stream>>>(attn, rpe, v_rpe, o1);
  k_proj<<<2352, 256, 0, stream>>>(o1, wprojb, proj_b, out);
}